// Round 14
// baseline (99.262 us; speedup 1.0000x reference)
//
#include <hip/hip_runtime.h>

#define NPTS  8192
#define BATCH 4

typedef short  bf8    __attribute__((ext_vector_type(8)));   // 8 bf16 = 4 VGPRs
typedef float  f32x16 __attribute__((ext_vector_type(16)));
typedef float  v2f    __attribute__((ext_vector_type(2)));

__device__ inline unsigned short bf16_rne(float x) {
    unsigned u = __float_as_uint(x);
    unsigned r = (u + 0x7FFFu + ((u >> 16) & 1u)) >> 16;   // round-nearest-even
    return (unsigned short)r;
}
__device__ inline float bf16_to_f(unsigned short h) {
    return __uint_as_float(((unsigned)h) << 16);
}
// Order-preserving float<->uint encode so atomicMax(uint) == float max.
__device__ inline unsigned fenc(float x) {
    unsigned b = __float_as_uint(x);
    return (b & 0x80000000u) ? ~b : (b | 0x80000000u);
}
__device__ inline float fdec(unsigned k) {
    unsigned b = (k & 0x80000000u) ? (k ^ 0x80000000u) : ~k;
    return __uint_as_float(b);
}
// DPP lane-move (VALU-only, no LDS). CTRL is a template param (must be ICE).
template <int CTRL>
__device__ inline float dpp_mov(float x) {
    int i = __float_as_int(x);
    int r = __builtin_amdgcn_update_dpp(i, i, CTRL, 0xF, 0xF, false);
    return __int_as_float(r);
}

// ============================================================================
// MFMA path: v_mfma_f32_32x32x16_bf16, layouts VERIFIED end-to-end (R8-R13
// absmax 0.0). ||s-d||^2 = -2*(s.d + w_s + w_d), w_p = -0.5*||p||^2.
// K-slots (16): A = [xh yh zh xl yl zl xh yh | zh 1 1 wh wl 0 0 0]
//               B = [xh yh zh xh yh zh xl yl | zl wh wl 1 1 0 0 0]
//   => C[n,m] = s.d (split-bf16) + w_s + w_d;  dist = max(-2C, 0).
// A/B: point = lane&31, k = (lane>>5)*8 + j. C/D: col = lane&31,
// row = (reg&3) + 8*(reg>>2) + 4*(lane>>5).
// R14 vs R13: single 64KB LDS stage (64 m-tiles) -> ONE __syncthreads per
// block (was 3) and a straight-line 32-iter loop the compiler can schedule
// with fine lgkmcnt (m97 pattern). 2 blocks/CU still fit (128KB <= 160KB).
// Timing note: harness poisons 256MB d_ws every iter (~42us fill @81% HBM
// peak) — fixed floor in dur_us, visible as fillBufferAligned in rocprof.
// ============================================================================

__global__ void pack_mfma(const float* __restrict__ f, const float* __restrict__ f_,
                          bf8* __restrict__ fA, bf8* __restrict__ fB,
                          bf8* __restrict__ gA, bf8* __restrict__ gB,
                          unsigned* __restrict__ seg, float* __restrict__ out) {
    int j = blockIdx.x * blockDim.x + threadIdx.x;   // 0..65535
    if (j == 0) out[0] = 0.0f;                       // d_out poisoned 0xAA
    seg[j] = 0u;                                     // < fenc of any real value
    int cloud = j >> 15;
    int idx   = j & 32767;                           // b*8192 + p
    const float* src = cloud ? f_ : f;
    float x = src[idx * 3 + 0], y = src[idx * 3 + 1], z = src[idx * 3 + 2];
    float w = -0.5f * (x * x + y * y + z * z);
    unsigned short xh = bf16_rne(x), yh = bf16_rne(y), zh = bf16_rne(z);
    unsigned short xl = bf16_rne(x - bf16_to_f(xh));
    unsigned short yl = bf16_rne(y - bf16_to_f(yh));
    unsigned short zl = bf16_rne(z - bf16_to_f(zh));
    unsigned short wh = bf16_rne(w);
    unsigned short wl = bf16_rne(w - bf16_to_f(wh));
    const short ONE = (short)0x3F80;                 // bf16 1.0

    bf8 A0, A1, B0, B1;
    A0[0]=(short)xh; A0[1]=(short)yh; A0[2]=(short)zh; A0[3]=(short)xl;
    A0[4]=(short)yl; A0[5]=(short)zl; A0[6]=(short)xh; A0[7]=(short)yh;
    A1[0]=(short)zh; A1[1]=ONE;       A1[2]=ONE;       A1[3]=(short)wh;
    A1[4]=(short)wl; A1[5]=0;         A1[6]=0;         A1[7]=0;
    B0[0]=(short)xh; B0[1]=(short)yh; B0[2]=(short)zh; B0[3]=(short)xh;
    B0[4]=(short)yh; B0[5]=(short)zh; B0[6]=(short)xl; B0[7]=(short)yl;
    B1[0]=(short)zl; B1[1]=(short)wh; B1[2]=(short)wl; B1[3]=ONE;
    B1[4]=ONE;       B1[5]=0;         B1[6]=0;         B1[7]=0;

    int b = idx >> 13, p = idx & 8191;
    int t = p >> 5, li = p & 31;                     // 32-point tiles
    size_t base = ((size_t)(b * 256 + t)) * 64;
    bf8* Adst = cloud ? gA : fA;
    bf8* Bdst = cloud ? gB : fB;
    Adst[base + li]      = A0;                       // khalf 0
    Adst[base + 32 + li] = A1;                       // khalf 1
    Bdst[base + li]      = B0;
    Bdst[base + 32 + li] = B1;
}

// 512 blocks x 512 thr (8 waves). Block = (pass, b, nblk: 512 rows, mseg:
// 2048 m = 64 tiles staged ONCE in 64 KB LDS). Wave holds 2 n-tiles.
// Straight-line 32-iter loop: 2 ds_read_b128, 4 MFMA(32x32x16), 32 v_max3.
// Epilogue: 5 DPP steps (VALU) -> atomicMax(enc) from lanes 16/48.
__global__ __launch_bounds__(512, 4) void chamfer_mfma(
        const bf8* __restrict__ fA, const bf8* __restrict__ fB,
        const bf8* __restrict__ gA, const bf8* __restrict__ gB,
        unsigned* __restrict__ seg) {
    __shared__ bf8 lbs[4096];                        // 64 m-tiles = 64 KB

    int tid  = threadIdx.x;
    int wv   = tid >> 6, lane = tid & 63;
    int bx   = blockIdx.x;                           // [0, 512)
    int mseg = bx & 3;
    int nblk = (bx >> 2) & 15;
    int b    = (bx >> 6) & 3;
    int pass = bx >> 8;                              // {0,1}

    const bf8* __restrict__ Af = pass ? gA : fA;     // rows (query side)
    const bf8* __restrict__ Bf = pass ? fB : gB;     // cols (target side)

    // Stage this block's 64 B-tiles (2048 m-points) once: 8x 16B/thread.
    const bf8* __restrict__ bp = Bf + ((size_t)(b * 256 + mseg * 64)) * 64;
#pragma unroll
    for (int k = 0; k < 8; ++k) lbs[k * 512 + tid] = bp[k * 512 + tid];

    // This wave's 2 n-tiles (64 rows) — loads overlap the staging stores.
    bf8 a[2];
    f32x16 rmax[2];
    int nt_loc = nblk * 16 + wv * 2;                 // tile idx within batch
#pragma unroll
    for (int s = 0; s < 2; ++s) {
        a[s] = Af[(size_t)(b * 256 + nt_loc + s) * 64 + lane];
        rmax[s] = (f32x16)(-3.0e38f);
    }
    __syncthreads();                                 // the ONLY barrier

    f32x16 zc = (f32x16)(0.0f);
#pragma unroll 4
    for (int i = 0; i < 32; ++i) {                   // 32 pair-iters = 64 tiles
        bf8 qa = lbs[i * 128 + lane];
        bf8 qb = lbs[i * 128 + 64 + lane];
        f32x16 d0 = __builtin_amdgcn_mfma_f32_32x32x16_bf16(a[0], qa, zc, 0, 0, 0);
        f32x16 d1 = __builtin_amdgcn_mfma_f32_32x32x16_bf16(a[0], qb, zc, 0, 0, 0);
        rmax[0] = __builtin_elementwise_max(
                      __builtin_elementwise_max(rmax[0], d0), d1);  // v_max3
        d0 = __builtin_amdgcn_mfma_f32_32x32x16_bf16(a[1], qa, zc, 0, 0, 0);
        d1 = __builtin_amdgcn_mfma_f32_32x32x16_bf16(a[1], qb, zc, 0, 0, 0);
        rmax[1] = __builtin_elementwise_max(
                      __builtin_elementwise_max(rmax[1], d0), d1);
    }

    // Row-max across 32 cols — DPP (VALU-only, no LDS):
    // steps 1-4 leave the row16 max in all lanes of the row; row_bcast15
    // folds row k into row k+1 -> group max in lanes 16-31 / 48-63.
#pragma unroll
    for (int s = 0; s < 2; ++s) {
#pragma unroll
        for (int r = 0; r < 16; ++r) {
            float x = rmax[s][r];
            x = fmaxf(x, dpp_mov<0xB1>(x));          // quad_perm [1,0,3,2]
            x = fmaxf(x, dpp_mov<0x4E>(x));          // quad_perm [2,3,0,1]
            x = fmaxf(x, dpp_mov<0x124>(x));         // row_ror:4
            x = fmaxf(x, dpp_mov<0x128>(x));         // row_ror:8
            x = fmaxf(x, dpp_mov<0x142>(x));         // row_bcast15
            rmax[s][r] = x;
        }
    }

    // C/D row = (reg&3) + 8*(reg>>2) + 4*(lane>>5); lanes 16 and 48 hold the
    // folded group max (row_bcast15 lands row k's max in row k+1).
    if ((lane & 31) == 16) {
        int rbase = (lane >> 5) * 4;
        unsigned* sg = seg + (size_t)(pass * 4 + b) * NPTS;
#pragma unroll
        for (int s = 0; s < 2; ++s) {
            int n0 = (nt_loc + s) * 32;
#pragma unroll
            for (int r = 0; r < 16; ++r) {
                int row = (r & 3) + 8 * (r >> 2) + rbase;
                atomicMax(&sg[n0 + row], fenc(rmax[s][r]));
            }
        }
    }
}

__global__ __launch_bounds__(1024) void finalize_mfma(
        const unsigned* __restrict__ seg, float* __restrict__ out) {
    __shared__ float partial[16];
    int j = blockIdx.x * 1024 + threadIdx.x;         // (pass*4+b)*8192 + n
    float emax = fdec(seg[j]);
    float dist = fmaxf(-2.0f * emax, 0.0f);          // C = s.d + w_s + w_d
    for (int off = 32; off > 0; off >>= 1)
        dist += __shfl_down(dist, off, 64);
    int lane = threadIdx.x & 63, wv = threadIdx.x >> 6;
    if (lane == 0) partial[wv] = dist;
    __syncthreads();
    if (threadIdx.x < 16) {
        float s = partial[threadIdx.x];
        for (int off = 8; off > 0; off >>= 1)
            s += __shfl_down(s, off, 64);
        if (threadIdx.x == 0) atomicAdd(out, s * (1.0f / 32768.0f));
    }
}

// ============================================================================
// Fallback 1 (ws >= 3MB): verified R4 packed-fp32 path (45.7 us main).
// ============================================================================

__global__ void pack_pk(const float* __restrict__ f, const float* __restrict__ f_,
                        float4* __restrict__ pk, float* __restrict__ prf,
                        float* __restrict__ out) {
    int j = blockIdx.x * blockDim.x + threadIdx.x;
    if (j == 0) out[0] = 0.0f;
    const float* src = (j >= 32768) ? f_ : f;
    int idx = j & 32767;
    float x = src[idx * 3 + 0], y = src[idx * 3 + 1], z = src[idx * 3 + 2];
    float w = -0.5f * (x * x + y * y + z * z);
    pk[j] = make_float4(x, y, z, w);
    int  slot = j & 1;
    long base = (long)(j >> 1) * 8;
    prf[base + 0 + slot] = x;
    prf[base + 2 + slot] = y;
    prf[base + 4 + slot] = z;
    prf[base + 6 + slot] = w;
}

__global__ __launch_bounds__(512, 8) void chamfer_pk(
        const float4* __restrict__ pk, const float4* __restrict__ pr,
        float* __restrict__ seg) {
    __shared__ float red[8][256];
    int tid  = threadIdx.x;
    int wv   = __builtin_amdgcn_readfirstlane(tid >> 6);
    int lane = tid & 63;
    int bx   = blockIdx.x;
    int tile = bx & 31;
    int b    = (bx >> 5) & 3;
    int dir  = (bx >> 7) & 1;
    int mq   = bx >> 8;

    const float4* __restrict__ A = pk + ((size_t)dir * BATCH + b) * NPTS;
    int n_base = tile * 256;
    v2f px[4], py[4], pz[4], e2[4];
#pragma unroll
    for (int r = 0; r < 4; ++r) {
        float4 p = A[n_base + lane + 64 * r];
        px[r] = (v2f){p.x, p.x};
        py[r] = (v2f){p.y, p.y};
        pz[r] = (v2f){p.z, p.z};
        e2[r] = (v2f){-1e30f, -1e30f};
    }
    int sb_m = (1 - dir) * BATCH + b;
    const float4* __restrict__ mp =
        pr + ((size_t)sb_m * 4096 + mq * 1024 + wv * 128) * 2;

    for (int i = 0; i < 128; i += 4) {
#pragma unroll
        for (int u = 0; u < 4; ++u) {
            float4 qa = mp[(i + u) * 2 + 0];
            float4 qb = mp[(i + u) * 2 + 1];
            v2f qx = (v2f){qa.x, qa.y};
            v2f qy = (v2f){qa.z, qa.w};
            v2f qz = (v2f){qb.x, qb.y};
            v2f qw = (v2f){qb.z, qb.w};
#pragma unroll
            for (int r = 0; r < 4; ++r) {
                v2f c = __builtin_elementwise_fma(px[r], qx, qw);
                c = __builtin_elementwise_fma(py[r], qy, c);
                c = __builtin_elementwise_fma(pz[r], qz, c);
                e2[r] = __builtin_elementwise_max(e2[r], c);
            }
        }
    }
#pragma unroll
    for (int r = 0; r < 4; ++r)
        red[wv][lane + 64 * r] = fmaxf(e2[r].x, e2[r].y);
    __syncthreads();
    if (tid < 256) {
        float emax = red[0][tid];
#pragma unroll
        for (int ww = 1; ww < 8; ++ww) emax = fmaxf(emax, red[ww][tid]);
        seg[mq * (2 * BATCH * NPTS) + dir * (BATCH * NPTS) + b * NPTS
            + n_base + tid] = emax;
    }
}

__global__ __launch_bounds__(1024) void finalize_pk(
        const float4* __restrict__ pk, const float* __restrict__ seg,
        float* __restrict__ out) {
    __shared__ float partial[16];
    int j = blockIdx.x * 1024 + threadIdx.x;
    float emax = seg[j];
#pragma unroll
    for (int q = 1; q < 4; ++q) emax = fmaxf(emax, seg[q * 65536 + j]);
    float dist = fmaxf(-2.0f * (emax + pk[j].w), 0.0f);
    for (int off = 32; off > 0; off >>= 1)
        dist += __shfl_down(dist, off, 64);
    int lane = threadIdx.x & 63, wv = threadIdx.x >> 6;
    if (lane == 0) partial[wv] = dist;
    __syncthreads();
    if (threadIdx.x < 16) {
        float s = partial[threadIdx.x];
        for (int off = 8; off > 0; off >>= 1)
            s += __shfl_down(s, off, 64);
        if (threadIdx.x == 0) atomicAdd(out, s * (1.0f / 32768.0f));
    }
}

// ============================================================================
// Fallback 2 (no ws): verified R2 kernel.
// ============================================================================

__global__ void zero_out_kernel(float* __restrict__ out) { out[0] = 0.0f; }

__global__ __launch_bounds__(1024) void chamfer_fallback(
        const float* __restrict__ f, const float* __restrict__ f_,
        float* __restrict__ out) {
    __shared__ float wlds[NPTS];
    __shared__ float red[16][256];
    __shared__ float partial[4];
    int tid  = threadIdx.x;
    int wv   = __builtin_amdgcn_readfirstlane(tid >> 6);
    int lane = tid & 63;
    int bx   = blockIdx.x;
    int dir  = bx >> 7;
    int b    = (bx >> 5) & 3;
    int tile = bx & 31;
    int n_base = tile * 256;
    const float* __restrict__ A  = dir ? f_ : f;
    const float* __restrict__ Bm = dir ? f  : f_;
    const float* an = A  + (size_t)b * NPTS * 3;
    const float* bm = Bm + (size_t)b * NPTS * 3;
    for (int i = tid; i < NPTS; i += 1024) {
        float x = bm[i * 3 + 0], y = bm[i * 3 + 1], z = bm[i * 3 + 2];
        wlds[i] = -0.5f * (x * x + y * y + z * z);
    }
    float xn[4], yn[4], zn[4];
#pragma unroll
    for (int r = 0; r < 4; ++r) {
        int n = n_base + lane + 64 * r;
        xn[r] = an[n * 3 + 0]; yn[r] = an[n * 3 + 1]; zn[r] = an[n * 3 + 2];
    }
    __syncthreads();
    float e[4];
#pragma unroll
    for (int r = 0; r < 4; ++r) e[r] = -1e30f;
    int m0 = wv * (NPTS / 16);
#pragma unroll 4
    for (int i = 0; i < NPTS / 16; ++i) {
        int m = m0 + i;
        float qx = bm[m * 3 + 0], qy = bm[m * 3 + 1], qz = bm[m * 3 + 2];
        float qw = wlds[m];
#pragma unroll
        for (int r = 0; r < 4; ++r) {
            float c = fmaf(zn[r], qz, fmaf(yn[r], qy, fmaf(xn[r], qx, qw)));
            e[r] = fmaxf(e[r], c);
        }
    }
#pragma unroll
    for (int r = 0; r < 4; ++r) red[wv][lane + 64 * r] = e[r];
    __syncthreads();
    if (tid < 256) {
        float emax = red[0][tid];
#pragma unroll
        for (int ww = 1; ww < 16; ++ww) emax = fmaxf(emax, red[ww][tid]);
        int n = n_base + tid;
        float x = an[n * 3 + 0], y = an[n * 3 + 1], z = an[n * 3 + 2];
        float dist = fmaxf(x * x + y * y + z * z - 2.0f * emax, 0.0f);
        for (int off = 32; off > 0; off >>= 1)
            dist += __shfl_down(dist, off, 64);
        if ((tid & 63) == 0) partial[tid >> 6] = dist;
    }
    __syncthreads();
    if (tid == 0) {
        float s = partial[0] + partial[1] + partial[2] + partial[3];
        atomicAdd(out, s * (1.0f / 32768.0f));
    }
}

extern "C" void kernel_launch(void* const* d_in, const int* in_sizes, int n_in,
                              void* d_out, int out_size, void* d_ws, size_t ws_size,
                              hipStream_t stream) {
    const float* f  = (const float*)d_in[0];
    const float* f_ = (const float*)d_in[1];
    float* out = (float*)d_out;

    const size_t MB = 1048576;
    if (ws_size >= 5 * MB) {
        bf8*      fA  = (bf8*)d_ws;                        // f  as A-role, 1 MB
        bf8*      fB  = (bf8*)((char*)d_ws + 1 * MB);      // f  as B-role
        bf8*      gA  = (bf8*)((char*)d_ws + 2 * MB);      // f_ as A-role
        bf8*      gB  = (bf8*)((char*)d_ws + 3 * MB);      // f_ as B-role
        unsigned* seg = (unsigned*)((char*)d_ws + 4 * MB); // 256 KB
        pack_mfma<<<256, 256, 0, stream>>>(f, f_, fA, fB, gA, gB, seg, out);
        chamfer_mfma<<<512, 512, 0, stream>>>(fA, fB, gA, gB, seg);
        finalize_mfma<<<64, 1024, 0, stream>>>(seg, out);
    } else if (ws_size >= 3 * MB) {
        float4* pk = (float4*)d_ws;
        float4* pr = (float4*)((char*)d_ws + 1 * MB);
        float*  sg = (float*)((char*)d_ws + 2 * MB);
        pack_pk<<<256, 256, 0, stream>>>(f, f_, pk, (float*)pr, out);
        chamfer_pk<<<1024, 512, 0, stream>>>(pk, pr, sg);
        finalize_pk<<<64, 1024, 0, stream>>>(pk, sg, out);
    } else {
        zero_out_kernel<<<1, 1, 0, stream>>>(out);
        chamfer_fallback<<<256, 1024, 0, stream>>>(f, f_, out);
    }
}

// Round 15
// 82.222 us; speedup vs baseline: 1.2072x; 1.2072x over previous
//
#include <hip/hip_runtime.h>

#define NPTS  8192
#define BATCH 4

typedef short  bf8    __attribute__((ext_vector_type(8)));   // 8 bf16 = 4 VGPRs
typedef float  f32x16 __attribute__((ext_vector_type(16)));
typedef float  v2f    __attribute__((ext_vector_type(2)));

__device__ inline unsigned short bf16_rne(float x) {
    unsigned u = __float_as_uint(x);
    unsigned r = (u + 0x7FFFu + ((u >> 16) & 1u)) >> 16;   // round-nearest-even
    return (unsigned short)r;
}
__device__ inline float bf16_to_f(unsigned short h) {
    return __uint_as_float(((unsigned)h) << 16);
}
// Order-preserving float<->uint encode so atomicMax(uint) == float max.
__device__ inline unsigned fenc(float x) {
    unsigned b = __float_as_uint(x);
    return (b & 0x80000000u) ? ~b : (b | 0x80000000u);
}
__device__ inline float fdec(unsigned k) {
    unsigned b = (k & 0x80000000u) ? (k ^ 0x80000000u) : ~k;
    return __uint_as_float(b);
}
// DPP lane-move (VALU-only, no LDS). CTRL is a template param (must be ICE).
template <int CTRL>
__device__ inline float dpp_mov(float x) {
    int i = __float_as_int(x);
    int r = __builtin_amdgcn_update_dpp(i, i, CTRL, 0xF, 0xF, false);
    return __int_as_float(r);
}

// ============================================================================
// MFMA path: v_mfma_f32_32x32x16_bf16, layouts VERIFIED end-to-end (R8-R13
// absmax 0.0). ||s-d||^2 = -2*(s.d + w_s + w_d), w_p = -0.5*||p||^2.
// K-slots (16): A = [xh yh zh xl yl zl xh yh | zh 1 1 wh wl 0 0 0]
//               B = [xh yh zh xh yh zh xl yl | zl wh wl 1 1 0 0 0]
//   => C[n,m] = s.d (split-bf16) + w_s + w_d;  dist = max(-2C, 0).
// A/B: point = lane&31, k = (lane>>5)*8 + j. C/D: col = lane&31,
// row = (reg&3) + 8*(reg>>2) + 4*(lane>>5).
// R15 = exact revert to R13 (the verified 84us plateau kernel).
// R14's single-barrier + unroll-4 variant spilled (WRITE_SIZE 146MB = whole
// 47us kernel at 3.5TB/s) — the 128-VGPR budget cannot absorb a wider
// schedule; every widening attempt (R8, R14) tips into scratch.
// Timing budget: ~42us harness ws-fill (81% HBM peak, untouchable) + ~13us
// fixed overhead + ~29us main (the m97-class 2-barrier scheduling plateau).
// ============================================================================

__global__ void pack_mfma(const float* __restrict__ f, const float* __restrict__ f_,
                          bf8* __restrict__ fA, bf8* __restrict__ fB,
                          bf8* __restrict__ gA, bf8* __restrict__ gB,
                          unsigned* __restrict__ seg, float* __restrict__ out) {
    int j = blockIdx.x * blockDim.x + threadIdx.x;   // 0..65535
    if (j == 0) out[0] = 0.0f;                       // d_out poisoned 0xAA
    seg[j] = 0u;                                     // < fenc of any real value
    int cloud = j >> 15;
    int idx   = j & 32767;                           // b*8192 + p
    const float* src = cloud ? f_ : f;
    float x = src[idx * 3 + 0], y = src[idx * 3 + 1], z = src[idx * 3 + 2];
    float w = -0.5f * (x * x + y * y + z * z);
    unsigned short xh = bf16_rne(x), yh = bf16_rne(y), zh = bf16_rne(z);
    unsigned short xl = bf16_rne(x - bf16_to_f(xh));
    unsigned short yl = bf16_rne(y - bf16_to_f(yh));
    unsigned short zl = bf16_rne(z - bf16_to_f(zh));
    unsigned short wh = bf16_rne(w);
    unsigned short wl = bf16_rne(w - bf16_to_f(wh));
    const short ONE = (short)0x3F80;                 // bf16 1.0

    bf8 A0, A1, B0, B1;
    A0[0]=(short)xh; A0[1]=(short)yh; A0[2]=(short)zh; A0[3]=(short)xl;
    A0[4]=(short)yl; A0[5]=(short)zl; A0[6]=(short)xh; A0[7]=(short)yh;
    A1[0]=(short)zh; A1[1]=ONE;       A1[2]=ONE;       A1[3]=(short)wh;
    A1[4]=(short)wl; A1[5]=0;         A1[6]=0;         A1[7]=0;
    B0[0]=(short)xh; B0[1]=(short)yh; B0[2]=(short)zh; B0[3]=(short)xh;
    B0[4]=(short)yh; B0[5]=(short)zh; B0[6]=(short)xl; B0[7]=(short)yl;
    B1[0]=(short)zl; B1[1]=(short)wh; B1[2]=(short)wl; B1[3]=ONE;
    B1[4]=ONE;       B1[5]=0;         B1[6]=0;         B1[7]=0;

    int b = idx >> 13, p = idx & 8191;
    int t = p >> 5, li = p & 31;                     // 32-point tiles
    size_t base = ((size_t)(b * 256 + t)) * 64;
    bf8* Adst = cloud ? gA : fA;
    bf8* Bdst = cloud ? gB : fB;
    Adst[base + li]      = A0;                       // khalf 0
    Adst[base + 32 + li] = A1;                       // khalf 1
    Bdst[base + li]      = B0;
    Bdst[base + 32 + li] = B1;
}

// 512 blocks x 512 thr (8 waves). Block = (pass, b, nblk: 512 rows, mseg:
// 2048 m in TWO 1024-m chunks staged in 32 KB LDS). Wave holds 2 n-tiles.
// Per iter: 2 prefetched ds_read_b128, 4 MFMA(32x32x16), 32 v_max3.
// Epilogue: 5 DPP steps (VALU) -> atomicMax(enc) from lanes 16/48.
__global__ __launch_bounds__(512, 4) void chamfer_mfma(
        const bf8* __restrict__ fA, const bf8* __restrict__ fB,
        const bf8* __restrict__ gA, const bf8* __restrict__ gB,
        unsigned* __restrict__ seg) {
    __shared__ bf8 lbs[2048];                        // 32 m-tiles = 32 KB

    int tid  = threadIdx.x;
    int wv   = tid >> 6, lane = tid & 63;
    int bx   = blockIdx.x;                           // [0, 512)
    int mseg = bx & 3;
    int nblk = (bx >> 2) & 15;
    int b    = (bx >> 6) & 3;
    int pass = bx >> 8;                              // {0,1}

    const bf8* __restrict__ Af = pass ? gA : fA;     // rows (query side)
    const bf8* __restrict__ Bf = pass ? fB : gB;     // cols (target side)

    // This wave's 2 n-tiles (64 rows) — load first, overlaps with staging.
    bf8 a[2];
    f32x16 rmax[2];
    int nt_loc = nblk * 16 + wv * 2;                 // tile idx within batch
#pragma unroll
    for (int s = 0; s < 2; ++s) {
        a[s] = Af[(size_t)(b * 256 + nt_loc + s) * 64 + lane];
        rmax[s] = (f32x16)(-3.0e38f);
    }

    f32x16 zc = (f32x16)(0.0f);
    for (int c = 0; c < 2; ++c) {
        // Stage this chunk's 32 B-tiles (1024 m-points): 4x 16B/thread.
        const bf8* __restrict__ bp =
            Bf + ((size_t)(b * 256 + mseg * 64 + c * 32)) * 64;
        if (c) __syncthreads();                      // lbs reuse fence
#pragma unroll
        for (int k = 0; k < 4; ++k) lbs[k * 512 + tid] = bp[k * 512 + tid];
        __syncthreads();

        // 16 pair-iters with 1-deep ds_read prefetch; d0/d1 reused per n-tile
        // to keep live VGPRs ~100 (128 budget at 4 waves/SIMD).
        bf8 qa = lbs[lane];
        bf8 qb = lbs[64 + lane];
#pragma unroll 2
        for (int i = 0; i < 16; ++i) {
            int ip = (i + 1) & 15;                   // wrap: last is harmless
            bf8 na = lbs[ip * 128 + lane];
            bf8 nb = lbs[ip * 128 + 64 + lane];
            f32x16 d0 = __builtin_amdgcn_mfma_f32_32x32x16_bf16(a[0], qa, zc, 0, 0, 0);
            f32x16 d1 = __builtin_amdgcn_mfma_f32_32x32x16_bf16(a[0], qb, zc, 0, 0, 0);
            rmax[0] = __builtin_elementwise_max(
                          __builtin_elementwise_max(rmax[0], d0), d1);  // v_max3
            d0 = __builtin_amdgcn_mfma_f32_32x32x16_bf16(a[1], qa, zc, 0, 0, 0);
            d1 = __builtin_amdgcn_mfma_f32_32x32x16_bf16(a[1], qb, zc, 0, 0, 0);
            rmax[1] = __builtin_elementwise_max(
                          __builtin_elementwise_max(rmax[1], d0), d1);
            qa = na; qb = nb;
        }
    }

    // Row-max across 32 cols — DPP (VALU-only, no LDS):
    // steps 1-4 leave the row16 max in all lanes of the row; row_bcast15
    // folds row k into row k+1 -> group max in lanes 16-31 / 48-63.
#pragma unroll
    for (int s = 0; s < 2; ++s) {
#pragma unroll
        for (int r = 0; r < 16; ++r) {
            float x = rmax[s][r];
            x = fmaxf(x, dpp_mov<0xB1>(x));          // quad_perm [1,0,3,2]
            x = fmaxf(x, dpp_mov<0x4E>(x));          // quad_perm [2,3,0,1]
            x = fmaxf(x, dpp_mov<0x124>(x));         // row_ror:4
            x = fmaxf(x, dpp_mov<0x128>(x));         // row_ror:8
            x = fmaxf(x, dpp_mov<0x142>(x));         // row_bcast15
            rmax[s][r] = x;
        }
    }

    // C/D row = (reg&3) + 8*(reg>>2) + 4*(lane>>5); lanes 16 and 48 hold the
    // folded group max (row_bcast15 lands row k's max in row k+1).
    if ((lane & 31) == 16) {
        int rbase = (lane >> 5) * 4;
        unsigned* sg = seg + (size_t)(pass * 4 + b) * NPTS;
#pragma unroll
        for (int s = 0; s < 2; ++s) {
            int n0 = (nt_loc + s) * 32;
#pragma unroll
            for (int r = 0; r < 16; ++r) {
                int row = (r & 3) + 8 * (r >> 2) + rbase;
                atomicMax(&sg[n0 + row], fenc(rmax[s][r]));
            }
        }
    }
}

__global__ __launch_bounds__(1024) void finalize_mfma(
        const unsigned* __restrict__ seg, float* __restrict__ out) {
    __shared__ float partial[16];
    int j = blockIdx.x * 1024 + threadIdx.x;         // (pass*4+b)*8192 + n
    float emax = fdec(seg[j]);
    float dist = fmaxf(-2.0f * emax, 0.0f);          // C = s.d + w_s + w_d
    for (int off = 32; off > 0; off >>= 1)
        dist += __shfl_down(dist, off, 64);
    int lane = threadIdx.x & 63, wv = threadIdx.x >> 6;
    if (lane == 0) partial[wv] = dist;
    __syncthreads();
    if (threadIdx.x < 16) {
        float s = partial[threadIdx.x];
        for (int off = 8; off > 0; off >>= 1)
            s += __shfl_down(s, off, 64);
        if (threadIdx.x == 0) atomicAdd(out, s * (1.0f / 32768.0f));
    }
}

// ============================================================================
// Fallback 1 (ws >= 3MB): verified R4 packed-fp32 path (45.7 us main).
// ============================================================================

__global__ void pack_pk(const float* __restrict__ f, const float* __restrict__ f_,
                        float4* __restrict__ pk, float* __restrict__ prf,
                        float* __restrict__ out) {
    int j = blockIdx.x * blockDim.x + threadIdx.x;
    if (j == 0) out[0] = 0.0f;
    const float* src = (j >= 32768) ? f_ : f;
    int idx = j & 32767;
    float x = src[idx * 3 + 0], y = src[idx * 3 + 1], z = src[idx * 3 + 2];
    float w = -0.5f * (x * x + y * y + z * z);
    pk[j] = make_float4(x, y, z, w);
    int  slot = j & 1;
    long base = (long)(j >> 1) * 8;
    prf[base + 0 + slot] = x;
    prf[base + 2 + slot] = y;
    prf[base + 4 + slot] = z;
    prf[base + 6 + slot] = w;
}

__global__ __launch_bounds__(512, 8) void chamfer_pk(
        const float4* __restrict__ pk, const float4* __restrict__ pr,
        float* __restrict__ seg) {
    __shared__ float red[8][256];
    int tid  = threadIdx.x;
    int wv   = __builtin_amdgcn_readfirstlane(tid >> 6);
    int lane = tid & 63;
    int bx   = blockIdx.x;
    int tile = bx & 31;
    int b    = (bx >> 5) & 3;
    int dir  = (bx >> 7) & 1;
    int mq   = bx >> 8;

    const float4* __restrict__ A = pk + ((size_t)dir * BATCH + b) * NPTS;
    int n_base = tile * 256;
    v2f px[4], py[4], pz[4], e2[4];
#pragma unroll
    for (int r = 0; r < 4; ++r) {
        float4 p = A[n_base + lane + 64 * r];
        px[r] = (v2f){p.x, p.x};
        py[r] = (v2f){p.y, p.y};
        pz[r] = (v2f){p.z, p.z};
        e2[r] = (v2f){-1e30f, -1e30f};
    }
    int sb_m = (1 - dir) * BATCH + b;
    const float4* __restrict__ mp =
        pr + ((size_t)sb_m * 4096 + mq * 1024 + wv * 128) * 2;

    for (int i = 0; i < 128; i += 4) {
#pragma unroll
        for (int u = 0; u < 4; ++u) {
            float4 qa = mp[(i + u) * 2 + 0];
            float4 qb = mp[(i + u) * 2 + 1];
            v2f qx = (v2f){qa.x, qa.y};
            v2f qy = (v2f){qa.z, qa.w};
            v2f qz = (v2f){qb.x, qb.y};
            v2f qw = (v2f){qb.z, qb.w};
#pragma unroll
            for (int r = 0; r < 4; ++r) {
                v2f c = __builtin_elementwise_fma(px[r], qx, qw);
                c = __builtin_elementwise_fma(py[r], qy, c);
                c = __builtin_elementwise_fma(pz[r], qz, c);
                e2[r] = __builtin_elementwise_max(e2[r], c);
            }
        }
    }
#pragma unroll
    for (int r = 0; r < 4; ++r)
        red[wv][lane + 64 * r] = fmaxf(e2[r].x, e2[r].y);
    __syncthreads();
    if (tid < 256) {
        float emax = red[0][tid];
#pragma unroll
        for (int ww = 1; ww < 8; ++ww) emax = fmaxf(emax, red[ww][tid]);
        seg[mq * (2 * BATCH * NPTS) + dir * (BATCH * NPTS) + b * NPTS
            + n_base + tid] = emax;
    }
}

__global__ __launch_bounds__(1024) void finalize_pk(
        const float4* __restrict__ pk, const float* __restrict__ seg,
        float* __restrict__ out) {
    __shared__ float partial[16];
    int j = blockIdx.x * 1024 + threadIdx.x;
    float emax = seg[j];
#pragma unroll
    for (int q = 1; q < 4; ++q) emax = fmaxf(emax, seg[q * 65536 + j]);
    float dist = fmaxf(-2.0f * (emax + pk[j].w), 0.0f);
    for (int off = 32; off > 0; off >>= 1)
        dist += __shfl_down(dist, off, 64);
    int lane = threadIdx.x & 63, wv = threadIdx.x >> 6;
    if (lane == 0) partial[wv] = dist;
    __syncthreads();
    if (threadIdx.x < 16) {
        float s = partial[threadIdx.x];
        for (int off = 8; off > 0; off >>= 1)
            s += __shfl_down(s, off, 64);
        if (threadIdx.x == 0) atomicAdd(out, s * (1.0f / 32768.0f));
    }
}

// ============================================================================
// Fallback 2 (no ws): verified R2 kernel.
// ============================================================================

__global__ void zero_out_kernel(float* __restrict__ out) { out[0] = 0.0f; }

__global__ __launch_bounds__(1024) void chamfer_fallback(
        const float* __restrict__ f, const float* __restrict__ f_,
        float* __restrict__ out) {
    __shared__ float wlds[NPTS];
    __shared__ float red[16][256];
    __shared__ float partial[4];
    int tid  = threadIdx.x;
    int wv   = __builtin_amdgcn_readfirstlane(tid >> 6);
    int lane = tid & 63;
    int bx   = blockIdx.x;
    int dir  = bx >> 7;
    int b    = (bx >> 5) & 3;
    int tile = bx & 31;
    int n_base = tile * 256;
    const float* __restrict__ A  = dir ? f_ : f;
    const float* __restrict__ Bm = dir ? f  : f_;
    const float* an = A  + (size_t)b * NPTS * 3;
    const float* bm = Bm + (size_t)b * NPTS * 3;
    for (int i = tid; i < NPTS; i += 1024) {
        float x = bm[i * 3 + 0], y = bm[i * 3 + 1], z = bm[i * 3 + 2];
        wlds[i] = -0.5f * (x * x + y * y + z * z);
    }
    float xn[4], yn[4], zn[4];
#pragma unroll
    for (int r = 0; r < 4; ++r) {
        int n = n_base + lane + 64 * r;
        xn[r] = an[n * 3 + 0]; yn[r] = an[n * 3 + 1]; zn[r] = an[n * 3 + 2];
    }
    __syncthreads();
    float e[4];
#pragma unroll
    for (int r = 0; r < 4; ++r) e[r] = -1e30f;
    int m0 = wv * (NPTS / 16);
#pragma unroll 4
    for (int i = 0; i < NPTS / 16; ++i) {
        int m = m0 + i;
        float qx = bm[m * 3 + 0], qy = bm[m * 3 + 1], qz = bm[m * 3 + 2];
        float qw = wlds[m];
#pragma unroll
        for (int r = 0; r < 4; ++r) {
            float c = fmaf(zn[r], qz, fmaf(yn[r], qy, fmaf(xn[r], qx, qw)));
            e[r] = fmaxf(e[r], c);
        }
    }
#pragma unroll
    for (int r = 0; r < 4; ++r) red[wv][lane + 64 * r] = e[r];
    __syncthreads();
    if (tid < 256) {
        float emax = red[0][tid];
#pragma unroll
        for (int ww = 1; ww < 16; ++ww) emax = fmaxf(emax, red[ww][tid]);
        int n = n_base + tid;
        float x = an[n * 3 + 0], y = an[n * 3 + 1], z = an[n * 3 + 2];
        float dist = fmaxf(x * x + y * y + z * z - 2.0f * emax, 0.0f);
        for (int off = 32; off > 0; off >>= 1)
            dist += __shfl_down(dist, off, 64);
        if ((tid & 63) == 0) partial[tid >> 6] = dist;
    }
    __syncthreads();
    if (tid == 0) {
        float s = partial[0] + partial[1] + partial[2] + partial[3];
        atomicAdd(out, s * (1.0f / 32768.0f));
    }
}

extern "C" void kernel_launch(void* const* d_in, const int* in_sizes, int n_in,
                              void* d_out, int out_size, void* d_ws, size_t ws_size,
                              hipStream_t stream) {
    const float* f  = (const float*)d_in[0];
    const float* f_ = (const float*)d_in[1];
    float* out = (float*)d_out;

    const size_t MB = 1048576;
    if (ws_size >= 5 * MB) {
        bf8*      fA  = (bf8*)d_ws;                        // f  as A-role, 1 MB
        bf8*      fB  = (bf8*)((char*)d_ws + 1 * MB);      // f  as B-role
        bf8*      gA  = (bf8*)((char*)d_ws + 2 * MB);      // f_ as A-role
        bf8*      gB  = (bf8*)((char*)d_ws + 3 * MB);      // f_ as B-role
        unsigned* seg = (unsigned*)((char*)d_ws + 4 * MB); // 256 KB
        pack_mfma<<<256, 256, 0, stream>>>(f, f_, fA, fB, gA, gB, seg, out);
        chamfer_mfma<<<512, 512, 0, stream>>>(fA, fB, gA, gB, seg);
        finalize_mfma<<<64, 1024, 0, stream>>>(seg, out);
    } else if (ws_size >= 3 * MB) {
        float4* pk = (float4*)d_ws;
        float4* pr = (float4*)((char*)d_ws + 1 * MB);
        float*  sg = (float*)((char*)d_ws + 2 * MB);
        pack_pk<<<256, 256, 0, stream>>>(f, f_, pk, (float*)pr, out);
        chamfer_pk<<<1024, 512, 0, stream>>>(pk, pr, sg);
        finalize_pk<<<64, 1024, 0, stream>>>(pk, sg, out);
    } else {
        zero_out_kernel<<<1, 1, 0, stream>>>(out);
        chamfer_fallback<<<256, 1024, 0, stream>>>(f, f_, out);
    }
}